// Round 1
// baseline (2557.126 us; speedup 1.0000x reference)
//
#include <hip/hip_runtime.h>
#include <cstdint>

// ---------------------------------------------------------------------------
// MMoE: x[B,D] -> E experts (Linear D->H1, BN+ReLU, Linear H1->H2, BN+ReLU),
// T gates (softmax over E), out[t,b,e*H2+k] = expert[e,b,k]*gate[t,b,e].
// B=32768 D=1472 E=8 H1=512 H2=256 T=2.  All fp32 in/out; internal GEMMs bf16
// MFMA (threshold ~2% allows it; BN renormalizes with stats of the same bf16
// values so the error does not compound).
// Biases b1/b2 cancel exactly through BatchNorm (constant column shift) -> skipped.
// ---------------------------------------------------------------------------

typedef __attribute__((ext_vector_type(8))) __bf16 bf16x8;
typedef __attribute__((ext_vector_type(4))) float f32x4;

__device__ __forceinline__ unsigned short f2bf(float f) {
  unsigned int u = __float_as_uint(f);
  u += 0x7fffu + ((u >> 16) & 1u);   // round-to-nearest-even
  return (unsigned short)(u >> 16);
}
__device__ __forceinline__ float bf2f(unsigned short s) {
  return __uint_as_float(((unsigned int)s) << 16);
}

// async global->LDS, 16B per lane.  LDS dest must be wave-uniform base + lane*16.
__device__ __forceinline__ void async16(const void* g, void* l) {
  __builtin_amdgcn_global_load_lds((__attribute__((address_space(1))) unsigned int*)g,
                                   (__attribute__((address_space(3))) unsigned int*)l,
                                   16, 0, 0);
}

// ---------------- fp32 -> bf16 elementwise convert (x) ----------------------
__global__ void convert_f32_bf16(const float* __restrict__ in,
                                 unsigned short* __restrict__ out, size_t n) {
  size_t i = ((size_t)blockIdx.x * blockDim.x + threadIdx.x) * 4;
  if (i + 3 < n) {
    float4 v = *(const float4*)(in + i);
    unsigned int w0 = (unsigned int)f2bf(v.x) | ((unsigned int)f2bf(v.y) << 16);
    unsigned int w1 = (unsigned int)f2bf(v.z) | ((unsigned int)f2bf(v.w) << 16);
    *(uint2*)(out + i) = make_uint2(w0, w1);
  }
}

// ---------------- W[E][D][H] fp32 -> Wt[E][H][D] bf16 (transpose) -----------
__global__ void transpose_bf16(const float* __restrict__ W,
                               unsigned short* __restrict__ Wt, int D, int H) {
  __shared__ float tile[32][33];
  int e = blockIdx.z;
  int d0 = blockIdx.x * 32, h0 = blockIdx.y * 32;
  const float* We = W + (size_t)e * D * H;
  unsigned short* Wte = Wt + (size_t)e * D * H;
  int tx = threadIdx.x, ty = threadIdx.y;  // block (32,8)
#pragma unroll
  for (int i = 0; i < 4; ++i)
    tile[ty + i * 8][tx] = We[(size_t)(d0 + ty + i * 8) * H + h0 + tx];
  __syncthreads();
#pragma unroll
  for (int i = 0; i < 4; ++i)
    Wte[(size_t)(h0 + ty + i * 8) * D + d0 + tx] = f2bf(tile[tx][ty + i * 8]);
}

// ---------------- gates: logits[t,b,e] = x[b,:]*Wg[t,:,e] + bg; softmax(e) --
// one wave per row b; fp32 throughout.
__global__ void gates_kernel(const float* __restrict__ x, const float* __restrict__ Wg,
                             const float* __restrict__ bg, float* __restrict__ gates,
                             int Bn, int D, int E) {
  int wid = threadIdx.x >> 6;
  int lane = threadIdx.x & 63;
  int b = blockIdx.x * 4 + wid;
  const float* xr = x + (size_t)b * D;
  float acc[16];
#pragma unroll
  for (int i = 0; i < 16; ++i) acc[i] = 0.f;
  for (int d = lane; d < D; d += 64) {
    float xv = xr[d];
    const float* w0 = Wg + (size_t)d * E;            // t=0 row
    const float* w1 = Wg + (size_t)(D + d) * E;      // t=1 row
#pragma unroll
    for (int e = 0; e < 8; ++e) {
      acc[e]     = fmaf(xv, w0[e], acc[e]);
      acc[8 + e] = fmaf(xv, w1[e], acc[8 + e]);
    }
  }
#pragma unroll
  for (int off = 32; off > 0; off >>= 1)
#pragma unroll
    for (int i = 0; i < 16; ++i) acc[i] += __shfl_down(acc[i], off, 64);
  if (lane == 0) {
#pragma unroll
    for (int t = 0; t < 2; ++t) {
      float v[8], mx = -1e30f;
#pragma unroll
      for (int e = 0; e < 8; ++e) { v[e] = acc[t * 8 + e] + bg[t * 8 + e]; mx = fmaxf(mx, v[e]); }
      float s = 0.f;
#pragma unroll
      for (int e = 0; e < 8; ++e) { v[e] = expf(v[e] - mx); s += v[e]; }
      float inv = 1.f / s;
#pragma unroll
      for (int e = 0; e < 8; ++e)
        gates[((size_t)t * Bn + b) * 8 + e] = v[e] * inv;
    }
  }
}

// ---------------- m97-style bf16 MFMA GEMM: C[M,N] = A[M,K] * Bt[N,K]^T -----
// 128x128 tile, BK=32, 256 threads = 4 waves in 2x2, 4x4 16x16x32 MFMAs/wave.
__global__ __launch_bounds__(256) void gemm_bt(
    const unsigned short* __restrict__ A, const unsigned short* __restrict__ Bt,
    unsigned short* __restrict__ C, int N, int K,
    size_t aStrideE, size_t bStrideE, size_t cStrideE) {
  __shared__ unsigned short sA[128 * 32];
  __shared__ unsigned short sB[128 * 32];
  const int tid = threadIdx.x;
  const int e = blockIdx.z;
  const unsigned short* Ae = A + (size_t)e * aStrideE + (size_t)blockIdx.x * 128 * K;
  const unsigned short* Be = Bt + (size_t)e * bStrideE + (size_t)blockIdx.y * 128 * K;

  const int lrow = tid >> 2;          // 0..63 staging row
  const int lseg = (tid & 3) * 8;     // k-segment within row
  const int wid = tid >> 6, lane = tid & 63;
  const int wr = (wid & 1) * 64, wc = (wid >> 1) * 64;
  const int mrow = lane & 15;
  const int kg = (lane >> 4) * 8;

  f32x4 acc[4][4] = {};
  const unsigned short* ga = Ae + (size_t)lrow * K + lseg;
  const unsigned short* gb = Be + (size_t)lrow * K + lseg;
  const size_t rowHalf = (size_t)64 * K;

  for (int k0 = 0; k0 < K; k0 += 32) {
    async16(ga + k0,           &sA[tid * 8]);
    async16(ga + k0 + rowHalf, &sA[2048 + tid * 8]);
    async16(gb + k0,           &sB[tid * 8]);
    async16(gb + k0 + rowHalf, &sB[2048 + tid * 8]);
    __syncthreads();   // drains vmcnt (global_load_lds) per barrier semantics
    bf16x8 af[4], bfr[4];
#pragma unroll
    for (int i = 0; i < 4; ++i)
      af[i] = *(const bf16x8*)&sA[(wr + i * 16 + mrow) * 32 + kg];
#pragma unroll
    for (int j = 0; j < 4; ++j)
      bfr[j] = *(const bf16x8*)&sB[(wc + j * 16 + mrow) * 32 + kg];
#pragma unroll
    for (int i = 0; i < 4; ++i)
#pragma unroll
      for (int j = 0; j < 4; ++j)
        acc[i][j] = __builtin_amdgcn_mfma_f32_16x16x32_bf16(af[i], bfr[j], acc[i][j], 0, 0, 0);
    __syncthreads();
  }

  // C/D layout (verified m89/m91): col = lane&15, row = (lane>>4)*4 + reg
  unsigned short* Ce = C + (size_t)e * cStrideE + (size_t)blockIdx.x * 128 * N +
                       (size_t)blockIdx.y * 128;
  const int r0 = wr + (lane >> 4) * 4;
  const int c0 = wc + (lane & 15);
#pragma unroll
  for (int i = 0; i < 4; ++i)
#pragma unroll
    for (int j = 0; j < 4; ++j)
#pragma unroll
      for (int r = 0; r < 4; ++r)
        Ce[(size_t)(r0 + i * 16 + r) * N + c0 + j * 16] = f2bf(acc[i][j][r]);
}

// ---------------- per-(e,col) sum & sumsq over B rows (bf16 input) ----------
__global__ void col_stats(const unsigned short* __restrict__ h, float* __restrict__ sum,
                          float* __restrict__ sumsq, int Bn, int H, int rowsPerBlock) {
  int e = blockIdx.x;
  int t = threadIdx.x;  // handles cols 2t, 2t+1; blockDim = H/2
  const unsigned short* base = h + ((size_t)e * Bn + (size_t)blockIdx.y * rowsPerBlock) * H;
  float s0 = 0, s1 = 0, q0 = 0, q1 = 0;
  for (int r = 0; r < rowsPerBlock; ++r) {
    unsigned int v = *(const unsigned int*)(base + (size_t)r * H + 2 * t);
    float f0 = __uint_as_float(v << 16);
    float f1 = __uint_as_float(v & 0xffff0000u);
    s0 += f0; s1 += f1; q0 += f0 * f0; q1 += f1 * f1;
  }
  atomicAdd(&sum[e * H + 2 * t], s0);
  atomicAdd(&sum[e * H + 2 * t + 1], s1);
  atomicAdd(&sumsq[e * H + 2 * t], q0);
  atomicAdd(&sumsq[e * H + 2 * t + 1], q1);
}

// ---------------- BN coefficients: y = a*x + c ------------------------------
__global__ void bn_coef(const float* __restrict__ sum, const float* __restrict__ sq,
                        const float* __restrict__ g, const float* __restrict__ be,
                        float* __restrict__ A, float* __restrict__ C, int n, float invB) {
  int i = blockIdx.x * blockDim.x + threadIdx.x;
  if (i < n) {
    float mean = sum[i] * invB;
    float var = sq[i] * invB - mean * mean;   // biased var, matches reference
    float a = g[i] * rsqrtf(var + 1e-5f);
    A[i] = a;
    C[i] = be[i] - mean * a;
  }
}

// ---------------- in-place BN+ReLU on bf16 [E][B][H] ------------------------
__global__ void bn_relu_inplace(unsigned short* __restrict__ h, const float* __restrict__ A,
                                const float* __restrict__ C, size_t total, int H, size_t strideE) {
  size_t i = ((size_t)blockIdx.x * blockDim.x + threadIdx.x) * 8;
  if (i >= total) return;
  int col = (int)(i % (size_t)H);
  int e = (int)(i / strideE);
  const float* Ae = A + e * H + col;
  const float* Ce = C + e * H + col;
  uint4 v = *(const uint4*)(h + i);
  unsigned int w[4] = {v.x, v.y, v.z, v.w};
#pragma unroll
  for (int j = 0; j < 4; ++j) {
    float f0 = __uint_as_float(w[j] << 16);
    float f1 = __uint_as_float(w[j] & 0xffff0000u);
    float y0 = fmaxf(fmaf(Ae[2 * j], f0, Ce[2 * j]), 0.f);
    float y1 = fmaxf(fmaf(Ae[2 * j + 1], f1, Ce[2 * j + 1]), 0.f);
    w[j] = (unsigned int)f2bf(y0) | ((unsigned int)f2bf(y1) << 16);
  }
  *(uint4*)(h + i) = make_uint4(w[0], w[1], w[2], w[3]);
}

// ---------------- BN2+ReLU+gate+write out [T][B][E*H2] ----------------------
__global__ void combine(const unsigned short* __restrict__ h2, const float* __restrict__ A,
                        const float* __restrict__ C, const float* __restrict__ gates,
                        float* __restrict__ out, int Bn, int H2) {
  int b = blockIdx.x;
  int t = blockIdx.y;
  int k = threadIdx.x;  // blockDim = H2
  const float* gp = gates + ((size_t)t * Bn + b) * 8;
  float* op = out + ((size_t)t * Bn + b) * (8 * H2);
#pragma unroll
  for (int e = 0; e < 8; ++e) {
    float gv = gp[e];
    float f = bf2f(h2[((size_t)e * Bn + b) * H2 + k]);
    float y = fmaxf(fmaf(A[e * H2 + k], f, C[e * H2 + k]), 0.f);
    op[e * H2 + k] = y * gv;
  }
}

// ---------------------------------------------------------------------------
extern "C" void kernel_launch(void* const* d_in, const int* in_sizes, int n_in,
                              void* d_out, int out_size, void* d_ws, size_t ws_size,
                              hipStream_t stream) {
  const int B = 32768, D = 1472, E = 8, H1 = 512, H2 = 256, T = 2;
  const float* x   = (const float*)d_in[0];
  const float* W1  = (const float*)d_in[1];
  // d_in[2] = b1 (cancels through BN), d_in[6] = b2 (cancels)
  const float* g1  = (const float*)d_in[3];
  const float* be1 = (const float*)d_in[4];
  const float* W2  = (const float*)d_in[5];
  const float* g2  = (const float*)d_in[7];
  const float* be2 = (const float*)d_in[8];
  const float* Wg  = (const float*)d_in[9];
  const float* bg  = (const float*)d_in[10];
  float* out = (float*)d_out;

  // workspace layout (~516 MB)
  char* p = (char*)d_ws;
  unsigned short* x_b = (unsigned short*)p; p += (size_t)B * D * 2;        // 96.5 MB
  unsigned short* W1t = (unsigned short*)p; p += (size_t)E * H1 * D * 2;   // 12.1 MB
  unsigned short* W2t = (unsigned short*)p; p += (size_t)E * H2 * H1 * 2;  //  2.1 MB
  unsigned short* h1b = (unsigned short*)p; p += (size_t)E * B * H1 * 2;   // 268 MB
  unsigned short* h2b = (unsigned short*)p; p += (size_t)E * B * H2 * 2;   // 134 MB
  float* gatesBuf = (float*)p; p += (size_t)T * B * E * 4;                 //  2.1 MB
  float* sum1 = (float*)p; p += (size_t)E * H1 * 4;
  float* sq1  = (float*)p; p += (size_t)E * H1 * 4;
  float* sum2 = (float*)p; p += (size_t)E * H2 * 4;
  float* sq2  = (float*)p; p += (size_t)E * H2 * 4;
  float* A1   = (float*)p; p += (size_t)E * H1 * 4;
  float* C1   = (float*)p; p += (size_t)E * H1 * 4;
  float* A2   = (float*)p; p += (size_t)E * H2 * 4;
  float* C2   = (float*)p; p += (size_t)E * H2 * 4;

  // zero the stats accumulators (sum1,sq1,sum2,sq2 contiguous)
  hipMemsetAsync(sum1, 0, (size_t)(E * H1 * 2 + E * H2 * 2) * 4, stream);

  // prep: conversions + transposes + gates
  convert_f32_bf16<<<((size_t)B * D) / (256 * 4), 256, 0, stream>>>(x, x_b, (size_t)B * D);
  transpose_bf16<<<dim3(D / 32, H1 / 32, E), dim3(32, 8), 0, stream>>>(W1, W1t, D, H1);
  transpose_bf16<<<dim3(H1 / 32, H2 / 32, E), dim3(32, 8), 0, stream>>>(W2, W2t, H1, H2);
  gates_kernel<<<B / 4, 256, 0, stream>>>(x, Wg, bg, gatesBuf, B, D, E);

  // expert layer 1: h1 = x @ W1  (x shared across experts -> aStrideE = 0)
  gemm_bt<<<dim3(B / 128, H1 / 128, E), 256, 0, stream>>>(
      x_b, W1t, h1b, H1, D, (size_t)0, (size_t)H1 * D, (size_t)B * H1);
  col_stats<<<dim3(E, 32), H1 / 2, 0, stream>>>(h1b, sum1, sq1, B, H1, B / 32);
  bn_coef<<<(E * H1 + 255) / 256, 256, 0, stream>>>(sum1, sq1, g1, be1, A1, C1, E * H1, 1.f / B);
  bn_relu_inplace<<<(unsigned)((size_t)E * B * H1 / 8 / 256), 256, 0, stream>>>(
      h1b, A1, C1, (size_t)E * B * H1, H1, (size_t)B * H1);

  // expert layer 2: h2 = h1 @ W2
  gemm_bt<<<dim3(B / 128, H2 / 128, E), 256, 0, stream>>>(
      h1b, W2t, h2b, H2, H1, (size_t)B * H1, (size_t)H2 * H1, (size_t)B * H2);
  col_stats<<<dim3(E, 32), H2 / 2, 0, stream>>>(h2b, sum2, sq2, B, H2, B / 32);
  bn_coef<<<(E * H2 + 255) / 256, 256, 0, stream>>>(sum2, sq2, g2, be2, A2, C2, E * H2, 1.f / B);

  // BN2 + ReLU + gate + write output
  combine<<<dim3(B, T), H2, 0, stream>>>(h2b, A2, C2, gatesBuf, out, B, H2);
}

// Round 2
// 1623.787 us; speedup vs baseline: 1.5748x; 1.5748x over previous
//
#include <hip/hip_runtime.h>
#include <cstdint>

// ---------------------------------------------------------------------------
// MMoE: x[B,D] -> E experts (Linear D->H1, BN+ReLU, Linear H1->H2, BN+ReLU),
// T gates (softmax over E), out[t,b,e*H2+k] = expert[e,b,k]*gate[t,b,e].
// B=32768 D=1472 E=8 H1=512 H2=256 T=2.
//
// R2 structure:
//  - GEMM1 is ONE dispatch: C[B, 4224] = x @ [W1_all | Wg_all]^T  (bf16 MFMA).
//    Cols 0..4095 = expert pre-BN h1 ([E][H1] flattened), cols 4096..4111 =
//    gate logits (t*8+e), 4112..4223 = pad (garbage, never read).
//  - Column sum/sumsq computed in the GEMM epilogue from fp32 accumulators
//    (kills the latency-bound col_stats passes).
//  - h1 layout [B][4224] -> GEMM2 reads expert slice in place (lda=4224).
//  - h2 layout [B][E*H2] -> combine is fully contiguous.
//  - Biases b1/b2 cancel exactly through BatchNorm -> skipped.
// ---------------------------------------------------------------------------

typedef __attribute__((ext_vector_type(8))) __bf16 bf16x8;
typedef __attribute__((ext_vector_type(4))) float f32x4;

__device__ __forceinline__ unsigned short f2bf(float f) {
  unsigned int u = __float_as_uint(f);
  u += 0x7fffu + ((u >> 16) & 1u);   // round-to-nearest-even
  return (unsigned short)(u >> 16);
}
__device__ __forceinline__ float bf2f(unsigned short s) {
  return __uint_as_float(((unsigned int)s) << 16);
}

// async global->LDS, 16B per lane.  LDS dest must be wave-uniform base + lane*16.
__device__ __forceinline__ void async16(const void* g, void* l) {
  __builtin_amdgcn_global_load_lds((__attribute__((address_space(1))) unsigned int*)g,
                                   (__attribute__((address_space(3))) unsigned int*)l,
                                   16, 0, 0);
}

// ---------------- fp32 -> bf16 elementwise convert (x) ----------------------
__global__ void convert_f32_bf16(const float* __restrict__ in,
                                 unsigned short* __restrict__ out, size_t n) {
  size_t i = ((size_t)blockIdx.x * blockDim.x + threadIdx.x) * 4;
  if (i + 3 < n) {
    float4 v = *(const float4*)(in + i);
    unsigned int w0 = (unsigned int)f2bf(v.x) | ((unsigned int)f2bf(v.y) << 16);
    unsigned int w1 = (unsigned int)f2bf(v.z) | ((unsigned int)f2bf(v.w) << 16);
    *(uint2*)(out + i) = make_uint2(w0, w1);
  }
}

// ---------------- W[E][D][H] fp32 -> Wt rows [e*H+h][D] bf16 ----------------
__global__ void transpose_bf16(const float* __restrict__ W,
                               unsigned short* __restrict__ Wt, int D, int H) {
  __shared__ float tile[32][33];
  int e = blockIdx.z;
  int d0 = blockIdx.x * 32, h0 = blockIdx.y * 32;
  const float* We = W + (size_t)e * D * H;
  unsigned short* Wte = Wt + (size_t)e * D * H;
  int tx = threadIdx.x, ty = threadIdx.y;  // block (32,8)
#pragma unroll
  for (int i = 0; i < 4; ++i)
    tile[ty + i * 8][tx] = We[(size_t)(d0 + ty + i * 8) * H + h0 + tx];
  __syncthreads();
#pragma unroll
  for (int i = 0; i < 4; ++i)
    Wte[(size_t)(h0 + ty + i * 8) * D + d0 + tx] = f2bf(tile[tx][ty + i * 8]);
}

// ---------------- Wg[T][D][E] fp32 -> rows [t*8+e][D] bf16 at Wt+row0 -------
__global__ void transpose_wg(const float* __restrict__ Wg,
                             unsigned short* __restrict__ Wt, int D) {
  int idx = blockIdx.x * 256 + threadIdx.x;            // 16*D total
  int te = idx / D, d = idx - te * D;
  int t = te >> 3, e = te & 7;
  Wt[(size_t)te * D + d] = f2bf(Wg[((size_t)t * D + d) * 8 + e]);
}

// ---------------- bf16 MFMA GEMM: C[M,N] = A[M,K](lda) * Bt[N,K]^T ----------
// 128x128 tile, BK=32, 256 threads = 4 waves in 2x2, 4x4 16x16x32 MFMAs/wave.
// Epilogue: per-column sum & sumsq atomics (fp32 acc), guarded by statCols.
__global__ __launch_bounds__(256) void gemm_bt(
    const unsigned short* __restrict__ A, int lda,
    const unsigned short* __restrict__ Bt,
    unsigned short* __restrict__ C, int ldc, int K,
    size_t aStrideE, size_t bStrideE, size_t cStrideE,
    float* __restrict__ sum, float* __restrict__ sq, int statStrideE, int statCols,
    int groupM, int GN) {
  __shared__ unsigned short sA[128 * 32];
  __shared__ unsigned short sB[128 * 32];
  const int tid = threadIdx.x;
  const int e = blockIdx.z;

  int bx, by;
  if (groupM) {               // 1D grid, group swizzle for L2 A-panel reuse
    int bid = blockIdx.x;
    int gsize = groupM * GN;
    int gid = bid / gsize;
    int rem = bid - gid * gsize;
    bx = gid * groupM + rem % groupM;
    by = rem / groupM;
  } else {
    bx = blockIdx.x; by = blockIdx.y;
  }

  const unsigned short* Ae = A + (size_t)e * aStrideE + (size_t)bx * 128 * lda;
  const unsigned short* Be = Bt + (size_t)e * bStrideE + (size_t)by * 128 * K;

  const int lrow = tid >> 2;          // 0..63 staging row
  const int lseg = (tid & 3) * 8;     // k-segment within row
  const int wid = tid >> 6, lane = tid & 63;
  const int wr = (wid & 1) * 64, wc = (wid >> 1) * 64;
  const int mrow = lane & 15;
  const int kg = (lane >> 4) * 8;

  f32x4 acc[4][4] = {};
  const unsigned short* ga = Ae + (size_t)lrow * lda + lseg;
  const unsigned short* gb = Be + (size_t)lrow * K + lseg;
  const size_t aHalf = (size_t)64 * lda;
  const size_t bHalf = (size_t)64 * K;

  for (int k0 = 0; k0 < K; k0 += 32) {
    async16(ga + k0,         &sA[tid * 8]);
    async16(ga + k0 + aHalf, &sA[2048 + tid * 8]);
    async16(gb + k0,         &sB[tid * 8]);
    async16(gb + k0 + bHalf, &sB[2048 + tid * 8]);
    __syncthreads();   // drains vmcnt (global_load_lds) per barrier semantics
    bf16x8 af[4], bfr[4];
#pragma unroll
    for (int i = 0; i < 4; ++i)
      af[i] = *(const bf16x8*)&sA[(wr + i * 16 + mrow) * 32 + kg];
#pragma unroll
    for (int j = 0; j < 4; ++j)
      bfr[j] = *(const bf16x8*)&sB[(wc + j * 16 + mrow) * 32 + kg];
#pragma unroll
    for (int i = 0; i < 4; ++i)
#pragma unroll
      for (int j = 0; j < 4; ++j)
        acc[i][j] = __builtin_amdgcn_mfma_f32_16x16x32_bf16(af[i], bfr[j], acc[i][j], 0, 0, 0);
    __syncthreads();
  }

  // C/D layout (verified m89/m91): col = lane&15, row = (lane>>4)*4 + reg
  unsigned short* Ce = C + (size_t)e * cStrideE + (size_t)bx * 128 * ldc +
                       (size_t)by * 128;
  const int r0 = wr + (lane >> 4) * 4;
  const int c0 = wc + (lane & 15);
#pragma unroll
  for (int i = 0; i < 4; ++i)
#pragma unroll
    for (int j = 0; j < 4; ++j)
#pragma unroll
      for (int r = 0; r < 4; ++r)
        Ce[(size_t)(r0 + i * 16 + r) * ldc + c0 + j * 16] = f2bf(acc[i][j][r]);

  // column stats: lanes {l, l^16, l^32, l^48} share columns and cover all
  // 64 rows of this wave's half-tile; butterfly over lane>>4, then atomic.
  float* se = sum + (size_t)e * statStrideE;
  float* qe = sq + (size_t)e * statStrideE;
#pragma unroll
  for (int j = 0; j < 4; ++j) {
    float s = 0.f, q = 0.f;
#pragma unroll
    for (int i = 0; i < 4; ++i)
#pragma unroll
      for (int r = 0; r < 4; ++r) {
        float v = acc[i][j][r];
        s += v;
        q = fmaf(v, v, q);
      }
    s += __shfl_xor(s, 16, 64); s += __shfl_xor(s, 32, 64);
    q += __shfl_xor(q, 16, 64); q += __shfl_xor(q, 32, 64);
    if ((lane >> 4) == 0) {
      int col = by * 128 + wc + j * 16 + (lane & 15);
      if (col < statCols) {
        atomicAdd(&se[col], s);
        atomicAdd(&qe[col], q);
      }
    }
  }
}

// ---------------- BN coefficients: y = a*x + c ------------------------------
__global__ void bn_coef(const float* __restrict__ sum, const float* __restrict__ sq,
                        const float* __restrict__ g, const float* __restrict__ be,
                        float* __restrict__ A, float* __restrict__ C, int n, float invB) {
  int i = blockIdx.x * blockDim.x + threadIdx.x;
  if (i < n) {
    float mean = sum[i] * invB;
    float var = sq[i] * invB - mean * mean;   // biased var, matches reference
    float a = g[i] * rsqrtf(var + 1e-5f);
    A[i] = a;
    C[i] = be[i] - mean * a;
  }
}

// ---------------- gate softmax from bf16 logits in h1[:,4096..4111] ---------
__global__ void gates_softmax(const unsigned short* __restrict__ h1,
                              const float* __restrict__ bg,
                              float* __restrict__ gates, int Bn) {
  int b = blockIdx.x * 256 + threadIdx.x;
  const unsigned short* p = h1 + (size_t)b * 4224 + 4096;
  uint4 v[2];
  v[0] = *(const uint4*)p;
  v[1] = *(const uint4*)(p + 8);
#pragma unroll
  for (int t = 0; t < 2; ++t) {
    float l[8];
    unsigned int w[4] = {v[t].x, v[t].y, v[t].z, v[t].w};
#pragma unroll
    for (int j = 0; j < 4; ++j) {
      l[2 * j]     = __uint_as_float(w[j] << 16) + bg[t * 8 + 2 * j];
      l[2 * j + 1] = __uint_as_float(w[j] & 0xffff0000u) + bg[t * 8 + 2 * j + 1];
    }
    float mx = -1e30f;
#pragma unroll
    for (int e = 0; e < 8; ++e) mx = fmaxf(mx, l[e]);
    float s = 0.f;
#pragma unroll
    for (int e = 0; e < 8; ++e) { l[e] = expf(l[e] - mx); s += l[e]; }
    float inv = 1.f / s;
    float4* gp = (float4*)(gates + ((size_t)t * Bn + b) * 8);
    gp[0] = make_float4(l[0] * inv, l[1] * inv, l[2] * inv, l[3] * inv);
    gp[1] = make_float4(l[4] * inv, l[5] * inv, l[6] * inv, l[7] * inv);
  }
}

// ---------------- in-place BN+ReLU on bf16 h1[B][4224], cols<4096 only ------
__global__ void bn_relu_inplace(unsigned short* __restrict__ h, const float* __restrict__ A,
                                const float* __restrict__ C) {
  int tid = blockIdx.x * blockDim.x + threadIdx.x;   // one vec8 per thread
  int r = tid / 528, cb = tid - r * 528;             // 528 vec8 slots per row
  if (cb >= 512) return;                             // skip gate/pad columns
  int col = cb * 8;
  size_t i = (size_t)r * 4224 + col;
  uint4 v = *(const uint4*)(h + i);
  unsigned int w[4] = {v.x, v.y, v.z, v.w};
#pragma unroll
  for (int j = 0; j < 4; ++j) {
    float f0 = __uint_as_float(w[j] << 16);
    float f1 = __uint_as_float(w[j] & 0xffff0000u);
    float y0 = fmaxf(fmaf(A[col + 2 * j], f0, C[col + 2 * j]), 0.f);
    float y1 = fmaxf(fmaf(A[col + 2 * j + 1], f1, C[col + 2 * j + 1]), 0.f);
    w[j] = (unsigned int)f2bf(y0) | ((unsigned int)f2bf(y1) << 16);
  }
  *(uint4*)(h + i) = make_uint4(w[0], w[1], w[2], w[3]);
}

// ---------------- BN2+ReLU+gate -> out [T][B][2048] -------------------------
__global__ void combine(const unsigned short* __restrict__ h2,   // [B][2048]
                        const float* __restrict__ A, const float* __restrict__ C,
                        const float* __restrict__ gates,          // [T][B][8]
                        float* __restrict__ out, int Bn) {
  int b = blockIdx.x;
  int c = threadIdx.x * 8;            // 256 threads x 8 = 2048 cols
  int e = c >> 8;
  uint4 v = *(const uint4*)(h2 + (size_t)b * 2048 + c);
  unsigned int w[4] = {v.x, v.y, v.z, v.w};
  float y[8];
#pragma unroll
  for (int j = 0; j < 4; ++j) {
    float f0 = __uint_as_float(w[j] << 16);
    float f1 = __uint_as_float(w[j] & 0xffff0000u);
    y[2 * j]     = fmaxf(fmaf(A[c + 2 * j], f0, C[c + 2 * j]), 0.f);
    y[2 * j + 1] = fmaxf(fmaf(A[c + 2 * j + 1], f1, C[c + 2 * j + 1]), 0.f);
  }
  float g0 = gates[(size_t)b * 8 + e];
  float g1 = gates[((size_t)Bn + b) * 8 + e];
  float4* o0 = (float4*)(out + (size_t)b * 2048 + c);
  float4* o1 = (float4*)(out + ((size_t)Bn + b) * 2048 + c);
  o0[0] = make_float4(y[0] * g0, y[1] * g0, y[2] * g0, y[3] * g0);
  o0[1] = make_float4(y[4] * g0, y[5] * g0, y[6] * g0, y[7] * g0);
  o1[0] = make_float4(y[0] * g1, y[1] * g1, y[2] * g1, y[3] * g1);
  o1[1] = make_float4(y[4] * g1, y[5] * g1, y[6] * g1, y[7] * g1);
}

// ---------------------------------------------------------------------------
extern "C" void kernel_launch(void* const* d_in, const int* in_sizes, int n_in,
                              void* d_out, int out_size, void* d_ws, size_t ws_size,
                              hipStream_t stream) {
  const int B = 32768, D = 1472, E = 8, H1 = 512, H2 = 256;
  const int N1 = 4224;                 // 4096 expert cols + 16 gate + 112 pad
  const float* x   = (const float*)d_in[0];
  const float* W1  = (const float*)d_in[1];
  // d_in[2] = b1 (cancels through BN), d_in[6] = b2 (cancels)
  const float* g1  = (const float*)d_in[3];
  const float* be1 = (const float*)d_in[4];
  const float* W2  = (const float*)d_in[5];
  const float* g2  = (const float*)d_in[7];
  const float* be2 = (const float*)d_in[8];
  const float* Wg  = (const float*)d_in[9];
  const float* bg  = (const float*)d_in[10];
  float* out = (float*)d_out;

  // workspace layout
  char* p = (char*)d_ws;
  unsigned short* x_b = (unsigned short*)p; p += (size_t)B * D * 2;          // 96.5 MB
  unsigned short* W1t = (unsigned short*)p; p += (size_t)N1 * D * 2;         // 12.4 MB
  unsigned short* W2t = (unsigned short*)p; p += (size_t)E * H2 * H1 * 2;    //  2.1 MB
  unsigned short* h1b = (unsigned short*)p; p += (size_t)B * N1 * 2;         // 277 MB
  unsigned short* h2b = (unsigned short*)p; p += (size_t)B * E * H2 * 2;     // 134 MB
  float* gatesBuf = (float*)p; p += (size_t)2 * B * 8 * 4;                   //  2.1 MB
  float* sum1 = (float*)p; p += (size_t)E * H1 * 4;
  float* sq1  = (float*)p; p += (size_t)E * H1 * 4;
  float* sum2 = (float*)p; p += (size_t)E * H2 * 4;
  float* sq2  = (float*)p; p += (size_t)E * H2 * 4;
  float* A1   = (float*)p; p += (size_t)E * H1 * 4;
  float* C1   = (float*)p; p += (size_t)E * H1 * 4;
  float* A2   = (float*)p; p += (size_t)E * H2 * 4;
  float* C2   = (float*)p; p += (size_t)E * H2 * 4;

  // zero stats accumulators (sum1,sq1,sum2,sq2 contiguous: 2*4096+2*2048 floats)
  hipMemsetAsync(sum1, 0, (size_t)(2 * E * H1 + 2 * E * H2) * 4, stream);

  // prep
  convert_f32_bf16<<<(unsigned)((size_t)B * D / (256 * 4)), 256, 0, stream>>>(
      x, x_b, (size_t)B * D);
  transpose_bf16<<<dim3(D / 32, H1 / 32, E), dim3(32, 8), 0, stream>>>(W1, W1t, D, H1);
  transpose_wg<<<(16 * D + 255) / 256, 256, 0, stream>>>(Wg, W1t + (size_t)4096 * D, D);
  transpose_bf16<<<dim3(H1 / 32, H2 / 32, E), dim3(32, 8), 0, stream>>>(W2, W2t, H1, H2);

  // GEMM1: h1[B][4224] = x_b[B][D] @ W1t[4224][D]^T   (single dispatch, swizzled)
  gemm_bt<<<dim3(256 * 33), 256, 0, stream>>>(
      x_b, D, W1t, h1b, N1, D, (size_t)0, (size_t)0, (size_t)0,
      sum1, sq1, 0, E * H1, /*groupM=*/32, /*GN=*/33);

  bn_coef<<<(E * H1 + 255) / 256, 256, 0, stream>>>(sum1, sq1, g1, be1, A1, C1, E * H1, 1.f / B);
  gates_softmax<<<B / 256, 256, 0, stream>>>(h1b, bg, gatesBuf, B);
  bn_relu_inplace<<<(unsigned)((size_t)B * 528 / 256), 256, 0, stream>>>(h1b, A1, C1);

  // GEMM2 per expert: h2[B][e*256..] = h1[B][e*512..](lda=4224) @ W2t[e]
  gemm_bt<<<dim3(B / 128, H2 / 128, E), 256, 0, stream>>>(
      h1b, N1, W2t, h2b, E * H2, H1,
      (size_t)512, (size_t)H2 * H1, (size_t)256,
      sum2, sq2, H2, H2, /*groupM=*/0, /*GN=*/0);

  bn_coef<<<(E * H2 + 255) / 256, 256, 0, stream>>>(sum2, sq2, g2, be2, A2, C2, E * H2, 1.f / B);

  // BN2 + ReLU + gate + write output
  combine<<<B, 256, 0, stream>>>(h2b, A2, C2, gatesBuf, out, B);
}